// Round 1
// baseline (429.885 us; speedup 1.0000x reference)
//
#include <hip/hip_runtime.h>

// Guided filter, r=8, eps=0.01, input (8,3,1024,1024) fp32.
// Clamped box window == zero-padded fixed 17-tap window + analytic count
// nump(r,c) = cy(r)*cx(c). Two kernels:
//   K1: vertical sliding sums of {x,y,xy,xx} (registers, coalesced)
//       -> LDS row -> horizontal 17-tap slide -> a,b -> horizontal slide
//       -> write ha=hbox(a), hb=hbox(b) planes to d_ws (needs 201.4 MB).
//   K2: vertical sliding sums of {ha,hb} + final out = a_mean*x + b_mean.
// blockIdx swizzle: g&7 selects a contiguous 128-row band (XCD L2 locality).

namespace {
constexpr int RAD  = 8;
constexpr int H    = 1024;
constexpr int W    = 1024;
constexpr int NSL  = 24;            // 8*3 slices
constexpr int ROWS = 16;            // output rows per block
constexpr int PW   = W + 2 * RAD;   // padded LDS row width (1040)
constexpr float EPS_C = 0.01f;
constexpr int GRID = NSL * (H / ROWS);  // 1536 blocks
}

__device__ __forceinline__ float frcp(float v) { return __builtin_amdgcn_rcpf(v); }

__device__ __forceinline__ void map_block(int g, int& slice, int& r0) {
  const int xcd = g & 7;        // 8 contiguous 128-row bands
  const int i = g >> 3;
  slice = i >> 3;               // 24 slices
  const int chunk = i & 7;      // 8 chunks of 16 rows per band
  r0 = xcd * (H / 8) + chunk * ROWS;
}

// 17-tap horizontal box sums for 4 consecutive columns, from a zero-padded
// LDS row. buf is the padded row base; c0 = 4*tid (padded idx of col c is c+8,
// window for col c0+j is padded [c0+j, c0+j+16], all inside buf[c0..c0+19]).
__device__ __forceinline__ void hbox(const float* buf, int c0, float o[4]) {
  const float4 va = *reinterpret_cast<const float4*>(buf + c0);
  const float4 vb = *reinterpret_cast<const float4*>(buf + c0 + 4);
  const float4 vc = *reinterpret_cast<const float4*>(buf + c0 + 8);
  const float4 vd = *reinterpret_cast<const float4*>(buf + c0 + 12);
  const float4 ve = *reinterpret_cast<const float4*>(buf + c0 + 16);
  const float w[20] = {va.x, va.y, va.z, va.w, vb.x, vb.y, vb.z, vb.w,
                       vc.x, vc.y, vc.z, vc.w, vd.x, vd.y, vd.z, vd.w,
                       ve.x, ve.y, ve.z, ve.w};
  float s = w[0];
#pragma unroll
  for (int k = 1; k <= 16; ++k) s += w[k];
  o[0] = s;
  o[1] = o[0] - w[0] + w[17];
  o[2] = o[1] - w[1] + w[18];
  o[3] = o[2] - w[2] + w[19];
}

__device__ __forceinline__ void acc_add(float4& Sx, float4& Sy, float4& Sxy,
                                        float4& Sxx, const float4 xv, const float4 yv) {
  Sx.x += xv.x; Sx.y += xv.y; Sx.z += xv.z; Sx.w += xv.w;
  Sy.x += yv.x; Sy.y += yv.y; Sy.z += yv.z; Sy.w += yv.w;
  Sxy.x += xv.x * yv.x; Sxy.y += xv.y * yv.y; Sxy.z += xv.z * yv.z; Sxy.w += xv.w * yv.w;
  Sxx.x += xv.x * xv.x; Sxx.y += xv.y * xv.y; Sxx.z += xv.z * xv.z; Sxx.w += xv.w * xv.w;
}

__device__ __forceinline__ void acc_sub(float4& Sx, float4& Sy, float4& Sxy,
                                        float4& Sxx, const float4 xv, const float4 yv) {
  Sx.x -= xv.x; Sx.y -= xv.y; Sx.z -= xv.z; Sx.w -= xv.w;
  Sy.x -= yv.x; Sy.y -= yv.y; Sy.z -= yv.z; Sy.w -= yv.w;
  Sxy.x -= xv.x * yv.x; Sxy.y -= xv.y * yv.y; Sxy.z -= xv.z * yv.z; Sxy.w -= xv.w * yv.w;
  Sxx.x -= xv.x * xv.x; Sxx.y -= xv.y * xv.y; Sxx.z -= xv.z * xv.z; Sxx.w -= xv.w * xv.w;
}

__global__ __launch_bounds__(256) void k_stage1(
    const float* __restrict__ x, const float* __restrict__ y,
    float* __restrict__ ha, float* __restrict__ hb) {
  __shared__ float fx[PW], fy[PW], fxy[PW], fxx[PW], sa[PW], sb[PW];
  const int t = threadIdx.x;
  int slice, r0;
  map_block(blockIdx.x, slice, r0);
  const size_t soff = (size_t)slice * H * W;
  const float* xs = x + soff;
  const float* ys = y + soff;
  float* has = ha + soff;
  float* hbs = hb + soff;
  const int c0 = t << 2;

  if (t < RAD) {  // zero pads (persist across the loop)
    fx[t] = 0.f; fy[t] = 0.f; fxy[t] = 0.f; fxx[t] = 0.f; sa[t] = 0.f; sb[t] = 0.f;
    fx[W + RAD + t] = 0.f; fy[W + RAD + t] = 0.f; fxy[W + RAD + t] = 0.f;
    fxx[W + RAD + t] = 0.f; sa[W + RAD + t] = 0.f; sb[W + RAD + t] = 0.f;
  }

  // init vertical window [max(0,r0-8), r0+8]  (r0+8 <= 1016 always)
  float4 Sx = {0, 0, 0, 0}, Sy = {0, 0, 0, 0}, Sxy = {0, 0, 0, 0}, Sxx = {0, 0, 0, 0};
  {
    int lo = r0 - RAD; if (lo < 0) lo = 0;
    for (int rr = lo; rr <= r0 + RAD; ++rr) {
      const float4 xv = *reinterpret_cast<const float4*>(xs + (size_t)rr * W + c0);
      const float4 yv = *reinterpret_cast<const float4*>(ys + (size_t)rr * W + c0);
      acc_add(Sx, Sy, Sxy, Sxx, xv, yv);
    }
  }

  float invcx[4];
#pragma unroll
  for (int j = 0; j < 4; ++j) {
    const int c = c0 + j;
    const int cl = (c - RAD < 0) ? 0 : c - RAD;
    const int ch = (c + RAD > W - 1) ? W - 1 : c + RAD;
    invcx[j] = frcp((float)(ch - cl + 1));
  }

  for (int r = r0; r < r0 + ROWS; ++r) {
    // publish this row's vertical sums
    *reinterpret_cast<float4*>(&fx[RAD + c0]) = Sx;
    *reinterpret_cast<float4*>(&fy[RAD + c0]) = Sy;
    *reinterpret_cast<float4*>(&fxy[RAD + c0]) = Sxy;
    *reinterpret_cast<float4*>(&fxx[RAD + c0]) = Sxx;
    __syncthreads();  // A

    float bx[4], by[4], bxy4[4], bxx4[4];
    hbox(fx, c0, bx);
    hbox(fy, c0, by);
    hbox(fxy, c0, bxy4);
    hbox(fxx, c0, bxx4);

    const int rl = (r - RAD < 0) ? 0 : r - RAD;
    const int rh = (r + RAD > H - 1) ? H - 1 : r + RAD;
    const float invcy = frcp((float)(rh - rl + 1));

    float av[4], bv[4];
#pragma unroll
    for (int j = 0; j < 4; ++j) {
      const float invN = invcy * invcx[j];
      const float mx = bx[j] * invN;
      const float my = by[j] * invN;
      const float cov = bxy4[j] * invN - mx * my;
      const float var = bxx4[j] * invN - mx * mx;
      const float a = cov * frcp(var + EPS_C);
      av[j] = a;
      bv[j] = my - a * mx;
    }
    *reinterpret_cast<float4*>(&sa[RAD + c0]) = make_float4(av[0], av[1], av[2], av[3]);
    *reinterpret_cast<float4*>(&sb[RAD + c0]) = make_float4(bv[0], bv[1], bv[2], bv[3]);
    __syncthreads();  // B

    float HA[4], HB[4];
    hbox(sa, c0, HA);
    hbox(sb, c0, HB);
    *reinterpret_cast<float4*>(has + (size_t)r * W + c0) =
        make_float4(HA[0], HA[1], HA[2], HA[3]);
    *reinterpret_cast<float4*>(hbs + (size_t)r * W + c0) =
        make_float4(HB[0], HB[1], HB[2], HB[3]);

    // slide vertical window to r+1
    const int radd = r + RAD + 1;
    const int rsub = r - RAD;
    if (radd < H) {
      const float4 xv = *reinterpret_cast<const float4*>(xs + (size_t)radd * W + c0);
      const float4 yv = *reinterpret_cast<const float4*>(ys + (size_t)radd * W + c0);
      acc_add(Sx, Sy, Sxy, Sxx, xv, yv);
    }
    if (rsub >= 0) {
      const float4 xv = *reinterpret_cast<const float4*>(xs + (size_t)rsub * W + c0);
      const float4 yv = *reinterpret_cast<const float4*>(ys + (size_t)rsub * W + c0);
      acc_sub(Sx, Sy, Sxy, Sxx, xv, yv);
    }
    __syncthreads();  // C (protect fx..fxx and sa/sb for next iteration)
  }
}

__global__ __launch_bounds__(256) void k_stage2(
    const float* __restrict__ ha, const float* __restrict__ hb,
    const float* __restrict__ x, float* __restrict__ out) {
  const int t = threadIdx.x;
  int slice, r0;
  map_block(blockIdx.x, slice, r0);
  const size_t soff = (size_t)slice * H * W;
  const float* has = ha + soff;
  const float* hbs = hb + soff;
  const float* xs = x + soff;
  float* os = out + soff;
  const int c0 = t << 2;

  float4 Sa = {0, 0, 0, 0}, Sb = {0, 0, 0, 0};
  {
    int lo = r0 - RAD; if (lo < 0) lo = 0;
    for (int rr = lo; rr <= r0 + RAD; ++rr) {
      const float4 av = *reinterpret_cast<const float4*>(has + (size_t)rr * W + c0);
      const float4 bv = *reinterpret_cast<const float4*>(hbs + (size_t)rr * W + c0);
      Sa.x += av.x; Sa.y += av.y; Sa.z += av.z; Sa.w += av.w;
      Sb.x += bv.x; Sb.y += bv.y; Sb.z += bv.z; Sb.w += bv.w;
    }
  }

  float invcx[4];
#pragma unroll
  for (int j = 0; j < 4; ++j) {
    const int c = c0 + j;
    const int cl = (c - RAD < 0) ? 0 : c - RAD;
    const int ch = (c + RAD > W - 1) ? W - 1 : c + RAD;
    invcx[j] = frcp((float)(ch - cl + 1));
  }

  for (int r = r0; r < r0 + ROWS; ++r) {
    const int rl = (r - RAD < 0) ? 0 : r - RAD;
    const int rh = (r + RAD > H - 1) ? H - 1 : r + RAD;
    const float invcy = frcp((float)(rh - rl + 1));

    const float4 xv = *reinterpret_cast<const float4*>(xs + (size_t)r * W + c0);
    float4 o;
    const float n0 = invcy * invcx[0];
    const float n1 = invcy * invcx[1];
    const float n2 = invcy * invcx[2];
    const float n3 = invcy * invcx[3];
    o.x = Sa.x * n0 * xv.x + Sb.x * n0;
    o.y = Sa.y * n1 * xv.y + Sb.y * n1;
    o.z = Sa.z * n2 * xv.z + Sb.z * n2;
    o.w = Sa.w * n3 * xv.w + Sb.w * n3;
    *reinterpret_cast<float4*>(os + (size_t)r * W + c0) = o;

    const int radd = r + RAD + 1;
    const int rsub = r - RAD;
    if (radd < H) {
      const float4 av = *reinterpret_cast<const float4*>(has + (size_t)radd * W + c0);
      const float4 bv = *reinterpret_cast<const float4*>(hbs + (size_t)radd * W + c0);
      Sa.x += av.x; Sa.y += av.y; Sa.z += av.z; Sa.w += av.w;
      Sb.x += bv.x; Sb.y += bv.y; Sb.z += bv.z; Sb.w += bv.w;
    }
    if (rsub >= 0) {
      const float4 av = *reinterpret_cast<const float4*>(has + (size_t)rsub * W + c0);
      const float4 bv = *reinterpret_cast<const float4*>(hbs + (size_t)rsub * W + c0);
      Sa.x -= av.x; Sa.y -= av.y; Sa.z -= av.z; Sa.w -= av.w;
      Sb.x -= bv.x; Sb.y -= bv.y; Sb.z -= bv.z; Sb.w -= bv.w;
    }
  }
}

extern "C" void kernel_launch(void* const* d_in, const int* in_sizes, int n_in,
                              void* d_out, int out_size, void* d_ws, size_t ws_size,
                              hipStream_t stream) {
  const float* x = (const float*)d_in[0];
  const float* y = (const float*)d_in[1];
  float* out = (float*)d_out;
  // workspace: two fp32 planes (ha, hb), 2 * 24*1024*1024 * 4 B = 201.4 MB
  float* ha = (float*)d_ws;
  float* hb = ha + (size_t)NSL * H * W;
  k_stage1<<<GRID, 256, 0, stream>>>(x, y, ha, hb);
  k_stage2<<<GRID, 256, 0, stream>>>(ha, hb, x, out);
}

// Round 2
// 338.311 us; speedup vs baseline: 1.2707x; 1.2707x over previous
//
#include <hip/hip_runtime.h>

// Fused guided filter, r=8, eps=0.01, (8,3,1024,1024) fp32, single kernel.
// Dual-pipeline recompute: per output row k we need Sa/Sb (vertical sums of
// ha=hbox(a), hb=hbox(b) over rows k-8..k+8). Instead of materializing ha/hb
// (was 400 MB of HBM traffic), each block maintains:
//   - LEADING pipeline: vertical sums of {x,y,xy,xx} centered p=k+8 ->
//     hbox -> a,b -> hbox -> ha[p],hb[p]  (added to Sa,Sb)
//   - LAGGING pipeline: same centered q=k-9 (recompute of what was added 17
//     steps earlier; subtracted from Sa,Sb)
// Clamped windows == zero-padded fixed 17-tap + analytic counts.
// Loads prefetched at step top, consumed at step bottom (2 barriers of hbox
// work in between hides HBM latency). ROWS=32 -> 768 blocks = 3 blocks/CU
// (LDS 49.9 KB/block), XCD-swizzled bands for L2 halo locality.

namespace {
constexpr int RAD  = 8;
constexpr int H    = 1024;
constexpr int W    = 1024;
constexpr int NSL  = 24;             // 8*3 slices
constexpr int ROWS = 32;             // output rows per block
constexpr int PW   = W + 2 * RAD;    // padded LDS row width (1040)
constexpr float EPS_C = 0.01f;
constexpr int GRID = NSL * (H / ROWS);  // 768 blocks
}

__device__ __forceinline__ float frcp(float v) { return __builtin_amdgcn_rcpf(v); }
__device__ __forceinline__ float4 z4() { return make_float4(0.f, 0.f, 0.f, 0.f); }

struct V4 { float4 x, y, xy, xx; };

__device__ __forceinline__ void vzero(V4& S) { S.x = z4(); S.y = z4(); S.xy = z4(); S.xx = z4(); }

__device__ __forceinline__ void vadd(V4& S, const float4 xv, const float4 yv) {
  S.x.x += xv.x; S.x.y += xv.y; S.x.z += xv.z; S.x.w += xv.w;
  S.y.x += yv.x; S.y.y += yv.y; S.y.z += yv.z; S.y.w += yv.w;
  S.xy.x += xv.x * yv.x; S.xy.y += xv.y * yv.y; S.xy.z += xv.z * yv.z; S.xy.w += xv.w * yv.w;
  S.xx.x += xv.x * xv.x; S.xx.y += xv.y * xv.y; S.xx.z += xv.z * xv.z; S.xx.w += xv.w * xv.w;
}

__device__ __forceinline__ void vsub(V4& S, const float4 xv, const float4 yv) {
  S.x.x -= xv.x; S.x.y -= xv.y; S.x.z -= xv.z; S.x.w -= xv.w;
  S.y.x -= yv.x; S.y.y -= yv.y; S.y.z -= yv.z; S.y.w -= yv.w;
  S.xy.x -= xv.x * yv.x; S.xy.y -= xv.y * yv.y; S.xy.z -= xv.z * yv.z; S.xy.w -= xv.w * yv.w;
  S.xx.x -= xv.x * xv.x; S.xx.y -= xv.y * xv.y; S.xx.z -= xv.z * xv.z; S.xx.w -= xv.w * xv.w;
}

__device__ __forceinline__ void map_block(int g, int& slice, int& r0) {
  const int xcd = g & 7;           // contiguous 128-row region per XCD
  const int i = g >> 3;            // [0,96)
  const int band = xcd * 4 + (i & 3);  // [0,32)
  slice = i >> 2;                  // [0,24)
  r0 = band * ROWS;
}

// 17-tap horizontal box sums for 4 consecutive cols from a zero-padded LDS
// row (16B lane stride -> conflict-free b128 reads).
__device__ __forceinline__ void hbox(const float* buf, int c0, float o[4]) {
  const float4 va = *reinterpret_cast<const float4*>(buf + c0);
  const float4 vb = *reinterpret_cast<const float4*>(buf + c0 + 4);
  const float4 vc = *reinterpret_cast<const float4*>(buf + c0 + 8);
  const float4 vd = *reinterpret_cast<const float4*>(buf + c0 + 12);
  const float4 ve = *reinterpret_cast<const float4*>(buf + c0 + 16);
  const float w[20] = {va.x, va.y, va.z, va.w, vb.x, vb.y, vb.z, vb.w,
                       vc.x, vc.y, vc.z, vc.w, vd.x, vd.y, vd.z, vd.w,
                       ve.x, ve.y, ve.z, ve.w};
  float s = w[0];
#pragma unroll
  for (int k = 1; k <= 16; ++k) s += w[k];
  o[0] = s;
  o[1] = o[0] - w[0] + w[17];
  o[2] = o[1] - w[1] + w[18];
  o[3] = o[2] - w[2] + w[19];
}

__device__ __forceinline__ float inv_cnt(int p) {
  int lo = p - RAD < 0 ? 0 : p - RAD;
  int hi = p + RAD > H - 1 ? H - 1 : p + RAD;
  return frcp((float)(hi - lo + 1));
}

__device__ __forceinline__ float4 ldrow(const float* __restrict__ s, int r, int c0) {
  return *reinterpret_cast<const float4*>(s + (size_t)r * W + c0);
}

__device__ __forceinline__ void publish(float* fbase, int c0, const V4& S) {
  *reinterpret_cast<float4*>(&fbase[0 * PW + RAD + c0]) = S.x;
  *reinterpret_cast<float4*>(&fbase[1 * PW + RAD + c0]) = S.y;
  *reinterpret_cast<float4*>(&fbase[2 * PW + RAD + c0]) = S.xy;
  *reinterpret_cast<float4*>(&fbase[3 * PW + RAD + c0]) = S.xx;
}

__device__ __forceinline__ void compute_ab(const float* fbase, int c0, float invcy,
                                           const float invcx[4], float av[4], float bv[4]) {
  float bx[4], by[4], bxy[4], bxx[4];
  hbox(fbase + 0 * PW, c0, bx);
  hbox(fbase + 1 * PW, c0, by);
  hbox(fbase + 2 * PW, c0, bxy);
  hbox(fbase + 3 * PW, c0, bxx);
#pragma unroll
  for (int j = 0; j < 4; ++j) {
    const float invN = invcy * invcx[j];
    const float mx = bx[j] * invN;
    const float my = by[j] * invN;
    const float cov = bxy[j] * invN - mx * my;
    const float var = bxx[j] * invN - mx * mx;
    const float a = cov * frcp(var + EPS_C);
    av[j] = a;
    bv[j] = my - a * mx;
  }
}

__device__ __forceinline__ void publish2(float* sbase, int c0, const float av[4], const float bv[4]) {
  *reinterpret_cast<float4*>(&sbase[RAD + c0]) = make_float4(av[0], av[1], av[2], av[3]);
  *reinterpret_cast<float4*>(&sbase[PW + RAD + c0]) = make_float4(bv[0], bv[1], bv[2], bv[3]);
}

__device__ __forceinline__ void hbox2(const float* sbase, int c0, float HA[4], float HB[4]) {
  hbox(sbase, c0, HA);
  hbox(sbase + PW, c0, HB);
}

__global__ __launch_bounds__(256, 3) void k_fused(
    const float* __restrict__ x, const float* __restrict__ y, float* __restrict__ out) {
  __shared__ float stage[12 * PW];  // 49,920 B: fL[4] fG[4] sL[2] sG[2]
  float* fL = stage;
  float* fG = stage + 4 * PW;
  float* sL = stage + 8 * PW;
  float* sG = stage + 10 * PW;

  const int t = threadIdx.x;
  int slice, r0;
  map_block(blockIdx.x, slice, r0);
  const size_t soff = (size_t)slice * H * W;
  const float* xs = x + soff;
  const float* ys = y + soff;
  float* os = out + soff;
  const int c0 = t << 2;

  // zero the halo pads of all 12 stage rows (persist for the whole kernel)
  if (t < 96) {
    const int j = t >> 3, tt = t & 7;
    stage[j * PW + tt] = 0.f;
    stage[j * PW + W + RAD + tt] = 0.f;
  }

  float invcx[4];
#pragma unroll
  for (int j = 0; j < 4; ++j) {
    const int c = c0 + j;
    const int cl = c - RAD < 0 ? 0 : c - RAD;
    const int ch = c + RAD > W - 1 ? W - 1 : c + RAD;
    invcx[j] = frcp((float)(ch - cl + 1));
  }

  // ---- init: build leading window at center cstart, copy to SG, then run the
  //      single pipeline for centers cstart..r0+7 accumulating Sa,Sb ----
  const int cstart = (r0 - 9 < 0) ? 0 : (r0 - 9);
  V4 SL; vzero(SL);
  {
    int lo = cstart - RAD; if (lo < 0) lo = 0;
    for (int rr = lo; rr <= cstart + RAD; ++rr) {
      vadd(SL, ldrow(xs, rr, c0), ldrow(ys, rr, c0));
    }
  }
  V4 SG;
  if (r0 == 0) vzero(SG); else SG = SL;  // SG = rows r0-17..r0-1 (or empty)
  float4 Sa = z4(), Sb = z4();

  __syncthreads();  // pads visible before first hbox

  for (int c = cstart; c <= r0 + 7; ++c) {
    // prefetch slide rows (consumed at bottom)
    const float4 xa = ldrow(xs, c + 9, c0), ya = ldrow(ys, c + 9, c0);
    float4 xr = z4(), yr = z4();
    if (c - RAD >= 0) { xr = ldrow(xs, c - RAD, c0); yr = ldrow(ys, c - RAD, c0); }

    publish(fL, c0, SL);
    __syncthreads();
    float av[4], bv[4];
    compute_ab(fL, c0, inv_cnt(c), invcx, av, bv);
    publish2(sL, c0, av, bv);
    __syncthreads();
    float HA[4], HB[4];
    hbox2(sL, c0, HA, HB);
    Sa.x += HA[0]; Sa.y += HA[1]; Sa.z += HA[2]; Sa.w += HA[3];
    Sb.x += HB[0]; Sb.y += HB[1]; Sb.z += HB[2]; Sb.w += HB[3];
    vadd(SL, xa, ya);
    vsub(SL, xr, yr);
    __syncthreads();
  }
  // invariants: SL centered r0+8, SG centered r0-9, Sa/Sb = ha rows [max(0,r0-9), r0+7]

  // ---- steady: one output row per step ----
  for (int k = r0; k < r0 + ROWS; ++k) {
    // prefetch (consumed after barrier B -> ~2 barriers of latency hiding)
    const float4 xk = ldrow(xs, k, c0), yk = ldrow(ys, k, c0);
    float4 xt = z4(), yt = z4(), xb = z4(), yb = z4();
    if (k + 17 < H)  { xt = ldrow(xs, k + 17, c0); yt = ldrow(ys, k + 17, c0); }
    if (k - 17 >= 0) { xb = ldrow(xs, k - 17, c0); yb = ldrow(ys, k - 17, c0); }

    publish(fL, c0, SL);
    publish(fG, c0, SG);
    __syncthreads();  // A

    const int p = k + 8, q = k - 9;
    float avL[4], bvL[4], avG[4], bvG[4];
    compute_ab(fL, c0, inv_cnt(p), invcx, avL, bvL);
    compute_ab(fG, c0, inv_cnt(q), invcx, avG, bvG);
    publish2(sL, c0, avL, bvL);
    publish2(sG, c0, avG, bvG);
    __syncthreads();  // B

    float HAL[4], HBL[4], HAG[4], HBG[4];
    hbox2(sL, c0, HAL, HBL);
    hbox2(sG, c0, HAG, HBG);
    if (p <= H - 1) {
      Sa.x += HAL[0]; Sa.y += HAL[1]; Sa.z += HAL[2]; Sa.w += HAL[3];
      Sb.x += HBL[0]; Sb.y += HBL[1]; Sb.z += HBL[2]; Sb.w += HBL[3];
    }
    if (q >= 0) {
      Sa.x -= HAG[0]; Sa.y -= HAG[1]; Sa.z -= HAG[2]; Sa.w -= HAG[3];
      Sb.x -= HBG[0]; Sb.y -= HBG[1]; Sb.z -= HBG[2]; Sb.w -= HBG[3];
    }

    const float invcy = inv_cnt(k);
    const float n0 = invcy * invcx[0], n1 = invcy * invcx[1];
    const float n2 = invcy * invcx[2], n3 = invcy * invcx[3];
    float4 o;
    o.x = Sa.x * n0 * xk.x + Sb.x * n0;
    o.y = Sa.y * n1 * xk.y + Sb.y * n1;
    o.z = Sa.z * n2 * xk.z + Sb.z * n2;
    o.w = Sa.w * n3 * xk.w + Sb.w * n3;
    *reinterpret_cast<float4*>(os + (size_t)k * W + c0) = o;

    // slides (consume prefetched rows; xk shared by lead-sub, lag-add, out)
    vadd(SL, xt, yt);
    vsub(SL, xk, yk);
    vadd(SG, xk, yk);
    vsub(SG, xb, yb);
    __syncthreads();  // C (protect stage rows before next publish)
  }
}

extern "C" void kernel_launch(void* const* d_in, const int* in_sizes, int n_in,
                              void* d_out, int out_size, void* d_ws, size_t ws_size,
                              hipStream_t stream) {
  const float* x = (const float*)d_in[0];
  const float* y = (const float*)d_in[1];
  float* out = (float*)d_out;
  k_fused<<<GRID, 256, 0, stream>>>(x, y, out);
}